// Round 5
// baseline (175.507 us; speedup 1.0000x reference)
//
#include <hip/hip_runtime.h>
#include <stdint.h>

// DCN v1 forward: B=8, C=256, H=W=64, K=3, pad=1, stride=1, O=256.
// Round 5: revert to R3 loop ordering (R4 prefetch regressed: store-to-barrier
// chain grew). Geometry: BN=32, 256-thr blocks (4 waves of 64Mx32N), grid 1024
// -> 4 blocks/CU = 4 independent barrier domains, 16 waves/CU. B-frag LDS
// duplication halved. prep-x LDS write rotation fixed (was 16-way conflict).

#define Bb 8
#define Cc 256
#define Hh 64
#define Ww 64
#define Pp 4096
#define Oo 256
#define NK2 9
#define NPAIR 36             // 36 pairs of K-steps (BK=64 each)
#define BN 32
#define SROW 40              // padded S row stride (elems)
#define WT_BYTES (2u * 72u * 256u * 32u)  // 1,179,648

typedef __attribute__((ext_vector_type(4))) float f32x4;
typedef __attribute__((ext_vector_type(8))) short s16x8;
typedef __attribute__((ext_vector_type(4))) int   i32x4;

static __device__ __forceinline__ unsigned short f2bf(float f) {
    union { float f; uint32_t u; } v; v.f = f;
    return (unsigned short)((v.u + 0x7fffu + ((v.u >> 16) & 1u)) >> 16);  // RNE
}
static __device__ __forceinline__ int imin(int a, int b) { return a < b ? a : b; }
static __device__ __forceinline__ int imax(int a, int b) { return a > b ? a : b; }

// ---------------- fused prep: x-transpose (blocks 0..2047) + weight (2048..2111)
// xT[b][p][c] bf16 ; wt[ks(72)][oc(256)][c32(32)] bf16, ks = k2*8+cch.
__global__ __launch_bounds__(256)
void prep(const float* __restrict__ x, const float* __restrict__ w,
          unsigned short* __restrict__ xt, unsigned short* __restrict__ wt) {
    __shared__ __align__(16) unsigned short L[9216];   // 18 KB, dual-purpose
    const int bx = blockIdx.x, tid = threadIdx.x;

    if (bx < 2048) {
        // ---- x: tile 64 c x 64 px ; b = bx&7 keeps XCD affinity with dcn_main
        unsigned short (*t2)[72] = (unsigned short(*)[72])L;  // 64 x 72 shorts
        const int b = bx & 7, ti = bx >> 3;
        const int c0 = (ti & 3) * 64, p0 = (ti >> 2) * 64;
        #pragma unroll
        for (int rd = 0; rd < 4; rd++) {
            int c = (tid >> 4) + rd * 16;
            int px4 = (tid & 15) * 4;
            f32x4 fv = *(const f32x4*)&x[(size_t)(b * Cc + c0 + c) * Pp + p0 + px4];
            #pragma unroll
            for (int j = 0; j < 4; j++) {
                int px = px4 + j;
                int chunk = ((c >> 3) + (px >> 3)) & 7;   // 2-way banking (free)
                t2[px][chunk * 8 + (c & 7)] = f2bf(fv[j]);
            }
        }
        __syncthreads();
        #pragma unroll
        for (int rd = 0; rd < 2; rd++) {
            int px = (tid >> 3) + rd * 32;
            int k = tid & 7;
            int chunk = (k + (px >> 3)) & 7;
            uint4 u = *(const uint4*)&t2[px][chunk * 8];
            *(uint4*)&xt[(size_t)(b * Pp + p0 + px) * Cc + c0 + k * 8] = u;
        }
    } else {
        // ---- weight: 64 blocks x 4 o-rows
        const int o0 = (bx - 2048) * 4;
        #pragma unroll
        for (int r9 = 0; r9 < 9; r9++) {
            int idx = r9 * 256 + tid;                  // 0..2303 float4s over 4 rows
            f32x4 fv = *(const f32x4*)&w[(size_t)o0 * 2304 + (size_t)idx * 4];
            #pragma unroll
            for (int j = 0; j < 4; j++) L[idx * 4 + j] = f2bf(fv[j]);
        }
        __syncthreads();
        #pragma unroll 4
        for (int i = 0; i < 36; i++) {
            int ks = i * 2 + (tid >> 7);
            int r = (tid >> 5) & 3, c32 = tid & 31;
            int c = (ks & 7) * 32 + c32, k2 = ks >> 3;
            wt[(size_t)ks * 8192 + (o0 + r) * 32 + c32] = L[r * 2304 + c * 9 + k2];
        }
    }
}

// ---------------- fused sampler + GEMM.
// Block: 256 thr = 4 waves, each wave 64(M) x 32(N). Grid: 1024 flat, b = bx&7.
__global__ __launch_bounds__(256, 4)
void dcn_main(const float* __restrict__ off, const unsigned short* __restrict__ wt,
              const unsigned short* __restrict__ xt, float* __restrict__ out) {
    __shared__ __align__(16) unsigned short Sl[2][2][BN][SROW];  // 10240 B
    __shared__ __align__(16) int   tidx[NK2][BN][4];             // 4608 B (byte offs)
    __shared__ __align__(16) float twgt[NK2][BN][4];             // 4608 B

    const int b   = blockIdx.x & 7;
    const int p0  = (blockIdx.x >> 3) * BN;
    const int tid = threadIdx.x;
    const int lane = tid & 63;
    const int wv   = tid >> 6;
    const int quad = lane >> 4;
    const int l16  = lane & 15;
    const int moff = wv * 64;

    const int px  = tid >> 3;          // sampler: 8 threads/pixel, 32 px
    const int sub = tid & 7;
    const int hh_ = sub >> 2;          // which 32-ch half of the pair
    const int cc_ = (sub & 3) * 8;     // channel offset within the half

    const char* xtb = (const char*)xt + (size_t)b * Pp * Cc * 2;

    // ---- taps for all 9 kernel points (once per block) ----
    for (int t = tid; t < NK2 * BN; t += 256) {
        int k2 = t >> 5, pxl = t & 31;
        int pl = p0 + pxl;
        int hh = pl >> 6, ww = pl & 63;
        int ky = k2 / 3, kx = k2 - ky * 3;
        float dy = off[((size_t)(b * 18 + 2 * k2    ) * Pp) + pl];
        float dx = off[((size_t)(b * 18 + 2 * k2 + 1) * Pp) + pl];
        float py  = (float)(hh - 1 + ky) + dy;
        float pxf = (float)(ww - 1 + kx) + dx;
        float y0f = floorf(py), x0f = floorf(pxf);
        int   y0 = (int)y0f,  x0 = (int)x0f;
        int   y1 = y0 + 1,    x1 = x0 + 1;
        float ly = py - y0f,  lx = pxf - x0f;
        float oy = 1.f - ly,  ox = 1.f - lx;
        bool vy0 = (y0 >= 0) && (y0 < Hh);
        bool vy1 = (y1 >= 0) && (y1 < Hh);
        bool vx0 = (x0 >= 0) && (x0 < Ww);
        bool vx1 = (x1 >= 0) && (x1 < Ww);
        int cy0 = imin(imax(y0, 0), Hh - 1), cy1 = imin(imax(y1, 0), Hh - 1);
        int cx0 = imin(imax(x0, 0), Ww - 1), cx1 = imin(imax(x1, 0), Ww - 1);
        tidx[k2][pxl][0] = (cy0 * Ww + cx0) * 512;  twgt[k2][pxl][0] = (vy0 && vx0) ? oy * ox : 0.f;
        tidx[k2][pxl][1] = (cy0 * Ww + cx1) * 512;  twgt[k2][pxl][1] = (vy0 && vx1) ? oy * lx : 0.f;
        tidx[k2][pxl][2] = (cy1 * Ww + cx0) * 512;  twgt[k2][pxl][2] = (vy1 && vx0) ? ly * ox : 0.f;
        tidx[k2][pxl][3] = (cy1 * Ww + cx1) * 512;  twgt[k2][pxl][3] = (vy1 && vx1) ? ly * lx : 0.f;
    }
    __syncthreads();

    int   tio[4];
    float twv[4];
    {
        i32x4 ti = *(const i32x4*)&tidx[0][px][0];
        f32x4 tw = *(const f32x4*)&twgt[0][px][0];
        #pragma unroll
        for (int t = 0; t < 4; t++) { tio[t] = ti[t]; twv[t] = tw[t]; }
    }

    // sample pair pr: 8 channels x 4 taps, one 16-B gather per tap; store to Sl
    auto sample_into = [&](int pr) {
        int coff = (pr & 3) * 128 + sub * 16;     // byte offset within 512-B pixel row
        float s0 = 0.f, s1 = 0.f, s2 = 0.f, s3 = 0.f, s4 = 0.f, s5 = 0.f, s6 = 0.f, s7 = 0.f;
        #pragma unroll
        for (int t = 0; t < 4; t++) {
            uint4 v = *(const uint4*)(xtb + tio[t] + coff);
            float wg = twv[t];
            s0 += wg * __uint_as_float(v.x << 16);
            s1 += wg * __uint_as_float(v.x);      // low bits = mantissa noise <2^-8
            s2 += wg * __uint_as_float(v.y << 16);
            s3 += wg * __uint_as_float(v.y);
            s4 += wg * __uint_as_float(v.z << 16);
            s5 += wg * __uint_as_float(v.z);
            s6 += wg * __uint_as_float(v.w << 16);
            s7 += wg * __uint_as_float(v.w);
        }
        uint4 d;
        d.x = __builtin_amdgcn_perm(__float_as_uint(s1), __float_as_uint(s0), 0x07060302u);
        d.y = __builtin_amdgcn_perm(__float_as_uint(s3), __float_as_uint(s2), 0x07060302u);
        d.z = __builtin_amdgcn_perm(__float_as_uint(s5), __float_as_uint(s4), 0x07060302u);
        d.w = __builtin_amdgcn_perm(__float_as_uint(s7), __float_as_uint(s6), 0x07060302u);
        *(uint4*)&Sl[pr & 1][hh_][px][cc_] = d;
    };

    f32x4 acc[4][2];
    #pragma unroll
    for (int mt = 0; mt < 4; mt++)
        #pragma unroll
        for (int nt = 0; nt < 2; nt++) acc[mt][nt] = (f32x4){0.f, 0.f, 0.f, 0.f};

    sample_into(0);

    for (int pr = 0; pr < NPAIR; pr++) {
        __syncthreads();   // Sl[pr&1] writes (prev iter / preamble) now visible

        // A fragments for both ks of the pair, straight from L2-resident wt
        const char* wb = (const char*)wt + ((size_t)pr << 15);
        s16x8 af[2][4];
        #pragma unroll
        for (int h = 0; h < 2; h++)
            #pragma unroll
            for (int mt = 0; mt < 4; mt++)
                af[h][mt] = *(const s16x8*)(wb + h * 16384 +
                                            (moff + mt * 16 + l16) * 64 + quad * 16);

        // R3 ordering: gathers + reduce + EARLY store for next pair
        int prn = pr + 1;
        if (prn < NPAIR) {
            if ((prn & 3) == 0) {           // new kernel point: reload taps
                int k2 = prn >> 2;
                i32x4 ti = *(const i32x4*)&tidx[k2][px][0];
                f32x4 tw = *(const f32x4*)&twgt[k2][px][0];
                #pragma unroll
                for (int t = 0; t < 4; t++) { tio[t] = ti[t]; twv[t] = tw[t]; }
            }
            sample_into(prn);
        }

        // B fragments + MFMA on current buffer (both halves of the pair)
        #pragma unroll
        for (int h = 0; h < 2; h++) {
            s16x8 bfr[2];
            #pragma unroll
            for (int nt = 0; nt < 2; nt++)
                bfr[nt] = *(const s16x8*)&Sl[pr & 1][h][nt * 16 + l16][quad * 8];
            #pragma unroll
            for (int mt = 0; mt < 4; mt++)
                #pragma unroll
                for (int nt = 0; nt < 2; nt++)
                    acc[mt][nt] = __builtin_amdgcn_mfma_f32_16x16x32_bf16(
                        af[h][mt], bfr[nt], acc[mt][nt], 0, 0, 0);
        }
    }

    // epilogue: C/D layout row(m)=quad*4+r, col(n)=l16
    float* op = out + ((size_t)b * Oo) * Pp + p0;
    #pragma unroll
    for (int mt = 0; mt < 4; mt++)
        #pragma unroll
        for (int nt = 0; nt < 2; nt++)
            #pragma unroll
            for (int r = 0; r < 4; r++) {
                int o_ = moff + mt * 16 + quad * 4 + r;
                int p_ = nt * 16 + l16;
                op[(size_t)o_ * Pp + p_] = acc[mt][nt][r];
            }
}

extern "C" void kernel_launch(void* const* d_in, const int* in_sizes, int n_in,
                              void* d_out, int out_size, void* d_ws, size_t ws_size,
                              hipStream_t stream) {
    (void)in_sizes; (void)n_in; (void)out_size; (void)ws_size;
    const float* x   = (const float*)d_in[0];
    const float* off = (const float*)d_in[1];
    const float* w   = (const float*)d_in[2];
    float* out = (float*)d_out;

    unsigned short* wt = (unsigned short*)d_ws;
    unsigned short* xt = (unsigned short*)((char*)d_ws + WT_BYTES);

    hipLaunchKernelGGL(prep, dim3(2112), dim3(256), 0, stream, x, w, xt, wt);
    hipLaunchKernelGGL(dcn_main, dim3(1024), dim3(256), 0, stream, off, wt, xt, out);
}